// Round 11
// baseline (106.678 us; speedup 1.0000x reference)
//
#include <hip/hip_runtime.h>
#include <hip/hip_bf16.h>
#include <math.h>

#define DIN 512
#define DF 256
#define LSEQ 1024
#define NTOT 8192

typedef __attribute__((ext_vector_type(8))) short short8;
typedef __attribute__((ext_vector_type(4))) short short4v;
typedef __attribute__((ext_vector_type(4))) float f32x4;

__device__ __forceinline__ short f2bf(float x) {
  union { float f; unsigned u; } un; un.f = x;
  unsigned r = un.u + 0x7fffu + ((un.u >> 16) & 1u);  // RNE (inputs finite)
  return (short)(r >> 16);
}
__device__ __forceinline__ float bf2f(short s) {
  union { unsigned u; float f; } un; un.u = ((unsigned)(unsigned short)s) << 16;
  return un.f;
}

typedef __attribute__((address_space(1))) const unsigned char AS1c;
typedef __attribute__((address_space(3))) unsigned char AS3;
__device__ __forceinline__ void gload16(const void* g, void* l) {
  __builtin_amdgcn_global_load_lds((AS1c*)g, (AS3*)l, 16, 0, 0);
}
#define CFENCE() asm volatile("" ::: "memory")
#define LN2 0.69314718056f

// ---------- kernel 1: W [DIN][DF] f32 -> Wt [DF][DIN] bf16 (LDS transpose) ----
__global__ __launch_bounds__(256) void prep_w_kernel(const float* __restrict__ W,
                                                     short* __restrict__ Wt) {
  __shared__ short t[64 * 70];
  const int tid = threadIdx.x;
  const int k0 = (blockIdx.x & 7) * 64;    // 8 k-tiles
  const int c0 = (blockIdx.x >> 3) * 64;   // 4 c-tiles
  const int cl = tid & 63, kq = tid >> 6;  // read: c fast (coalesced)
#pragma unroll
  for (int r = 0; r < 16; ++r) {
    int kl = kq * 16 + r;
    t[cl * 70 + kl] = f2bf(W[(size_t)(k0 + kl) * DF + c0 + cl]);
  }
  __syncthreads();
  const int kl2 = tid & 63, cq = tid >> 6; // write: k fast (coalesced)
#pragma unroll
  for (int r = 0; r < 16; ++r) {
    int cl2 = cq * 16 + r;
    Wt[(size_t)(c0 + cl2) * DIN + k0 + kl2] = t[cl2 * 70 + kl2];
  }
}

// ---------- kernel 2: projection emb = relu(feat @ W + b), bf16 out ----------
#define PBM 64
#define PBK 64

__global__ __launch_bounds__(256) void proj_kernel(const float* __restrict__ f1,
                                                   const float* __restrict__ f2,
                                                   const short* __restrict__ Wt,
                                                   const float* __restrict__ bias,
                                                   short* __restrict__ emb1,
                                                   short* __restrict__ emb2) {
  const float* feat = blockIdx.y ? f2 : f1;
  short* emb = blockIdx.y ? emb2 : emb1;
  __shared__ short ldsA[8 * 64 * 8];    // 8KB:  granule g = kb*64 + row
  __shared__ short ldsB[8 * 256 * 8];   // 32KB: granule g = kb*256 + col
  const int tid = threadIdx.x;
  const int lane = tid & 63, wv = tid >> 6;
  const int wrow = (wv & 1) * 32, wcol = (wv >> 1) * 128;
  const int l15 = lane & 15, lk16 = lane >> 4;
  const int rowbase = blockIdx.x * PBM;

  f32x4 acc[2][8];
#pragma unroll
  for (int mi = 0; mi < 2; ++mi)
#pragma unroll
    for (int nf = 0; nf < 8; ++nf) acc[mi][nf] = f32x4{0.f, 0.f, 0.f, 0.f};

  for (int K0 = 0; K0 < DIN; K0 += PBK) {
    __syncthreads();
#pragma unroll
    for (int i = 0; i < 8; ++i)
      gload16(Wt + (size_t)tid * DIN + K0 + i * 8, ldsB + (i * 256 + tid) * 8);
#pragma unroll
    for (int i = 0; i < 2; ++i) {
      int g = i * 256 + tid;
      int kb = g >> 6, r = g & 63;
      const float* src = feat + (size_t)(rowbase + r) * DIN + K0 + kb * 8;
      f32x4 v0 = *(const f32x4*)(src);
      f32x4 v1 = *(const f32x4*)(src + 4);
      short8 h;
      h[0] = f2bf(v0[0]); h[1] = f2bf(v0[1]); h[2] = f2bf(v0[2]); h[3] = f2bf(v0[3]);
      h[4] = f2bf(v1[0]); h[5] = f2bf(v1[1]); h[6] = f2bf(v1[2]); h[7] = f2bf(v1[3]);
      *(short8*)(ldsA + g * 8) = h;
    }
    __syncthreads();
#pragma unroll
    for (int kk = 0; kk < 2; ++kk) {
      const int kb = kk * 4 + lk16;
      short8 af[2], bf[8];
#pragma unroll
      for (int mi = 0; mi < 2; ++mi)
        af[mi] = *(const short8*)(ldsA + (kb * 64 + wrow + mi * 16 + l15) * 8);
#pragma unroll
      for (int nf = 0; nf < 8; ++nf)
        bf[nf] = *(const short8*)(ldsB + (kb * 256 + wcol + nf * 16 + l15) * 8);
#pragma unroll
      for (int mi = 0; mi < 2; ++mi)
#pragma unroll
        for (int nf = 0; nf < 8; ++nf)
          acc[mi][nf] = __builtin_amdgcn_mfma_f32_16x16x32_bf16(af[mi], bf[nf], acc[mi][nf], 0, 0, 0);
    }
  }
  const int r4 = (lane >> 4) * 4;
#pragma unroll
  for (int mi = 0; mi < 2; ++mi) {
    int row0 = rowbase + wrow + mi * 16 + r4;
#pragma unroll
    for (int nf = 0; nf < 8; ++nf) {
      int col = wcol + nf * 16 + l15;
      float bb = bias[col];
#pragma unroll
      for (int r = 0; r < 4; ++r) {
        float v = acc[mi][nf][r] + bb;
        v = v > 0.f ? v : 0.f;
        emb[(size_t)(row0 + r) * DF + col] = f2bf(v);
      }
    }
  }
}

// ---------- kernel 3: positive = dot(e1,e2) + banded diag means (LDS halo) ----
#define POSR 32
#define PSTR 258   // row stride in shorts (4B pad)

__global__ __launch_bounds__(256) void positive_kernel(const short* __restrict__ emb1,
                                                       const short* __restrict__ emb2,
                                                       const int* __restrict__ prs,
                                                       const int* __restrict__ prt,
                                                       float* __restrict__ pos) {
  __shared__ short s1[40 * PSTR];
  __shared__ short s2[40 * PSTR];
  const int tid = threadIdx.x;
  const int b = blockIdx.x >> 5;          // 32 blocks per batch
  const int j0 = (blockIdx.x & 31) * POSR;
  const int rs = prs[0], rt = prt[0];

  {
    const int rr = tid >> 6, c4 = (tid & 63) * 4;
#pragma unroll
    for (int it = 0; it < 10; ++it) {
      int r = it * 4 + rr;
      int g = j0 - 4 + r;
      short4v v1 = short4v{0, 0, 0, 0}, v2 = short4v{0, 0, 0, 0};
      if (g >= 0 && g < LSEQ) {
        size_t off = (size_t)(b * LSEQ + g) * DF + c4;
        v1 = *(const short4v*)(emb1 + off);
        v2 = *(const short4v*)(emb2 + off);
      }
      *(short4v*)(s1 + r * PSTR + c4) = v1;
      *(short4v*)(s2 + r * PSTR + c4) = v2;
    }
  }
  __syncthreads();

  const int lane = tid & 63, wv = tid >> 6;
  for (int q = 0; q < 8; ++q) {
    const int j = j0 + wv * 8 + q;
    const int rl = wv * 8 + q + 4;
    float a1[4], a2[4];
    {
      short4v v1 = *(const short4v*)(s1 + rl * PSTR + lane * 4);
      short4v v2 = *(const short4v*)(s2 + rl * PSTR + lane * 4);
#pragma unroll
      for (int i = 0; i < 4; ++i) { a1[i] = bf2f(v1[i]); a2[i] = bf2f(v2[i]); }
    }
    float dot12 = 0.f, p11 = 0.f, p22 = 0.f, p12 = 0.f;
#pragma unroll
    for (int i = 0; i < 4; ++i) dot12 += a1[i] * a2[i];
    int rmax = rs > rt ? rs : rt;
    for (int d = -rmax; d <= rmax; ++d) {
      int k = j + d;
      if (k < 0 || k >= LSEQ) continue;
      int kl = rl + d;
      short4v w1 = *(const short4v*)(s1 + kl * PSTR + lane * 4);
      short4v w2 = *(const short4v*)(s2 + kl * PSTR + lane * 4);
      float d11 = 0.f, d22 = 0.f, d12 = 0.f;
#pragma unroll
      for (int i = 0; i < 4; ++i) {
        float e1k = bf2f(w1[i]), e2k = bf2f(w2[i]);
        d11 += a1[i] * e1k;
        d22 += a2[i] * e2k;
        d12 += a1[i] * e2k;
      }
      if (d >= -rs && d <= rs) { p11 += d11; p22 += d22; }
      if (d >= -rt && d <= rt) { p12 += d12; }
    }
#pragma unroll
    for (int m = 1; m < 64; m <<= 1) {
      dot12 += __shfl_xor(dot12, m);
      p11 += __shfl_xor(p11, m);
      p22 += __shfl_xor(p22, m);
      p12 += __shfl_xor(p12, m);
    }
    if (lane == 0) {
      float res = dot12;
      if (rs > 0) {
        int lo = j - rs < 0 ? 0 : j - rs;
        int hi = j + rs > LSEQ - 1 ? LSEQ - 1 : j + rs;
        res += (p11 + p22) / (float)(hi - lo + 1);
      }
      if (rt > 0) {
        int lo = j - rt < 0 ? 0 : j - rt;
        int hi = j + rt > LSEQ - 1 ? LSEQ - 1 : j + rt;
        res += p12 / (float)(hi - lo + 1);
      }
      pos[b * LSEQ + j] = res;
    }
  }
}

// ---------- kernel 4: flash-style row logsumexp of e1 @ e2^T ----------
// 64 ROWS PER WAVE (NBM=256): halves total LDS-read traffic (1.07GB->0.5GB,
// the co-dominant pipe at NBM=128) — MFMA becomes the clear critical pipe.
// Spill-safe: nf-split halves keep acc at [4][2] (32 VGPR); softmax per half;
// no staging regs (gload_lds). Schedule = R4's proven counted-vmcnt(8) +
// 2 raw barriers/tile. [k8][col] granule layout, conflict-free by the R4
// construction. NBN=64 -> NT=8, 16 barriers per block.
#define NBM 256
#define NBN 64
#define NCHUNK 16
#define CHW (NTOT / NCHUNK)   // 512
#define NT (CHW / NBN)        // 8

__global__ __launch_bounds__(256, 2) void negative_kernel(const short* __restrict__ e1,
                                                          const short* __restrict__ e2,
                                                          float* __restrict__ mpart,
                                                          float* __restrict__ spart) {
  __shared__ short ldsB[2][NBN * DF];   // 2 x 32KB, granule g = k8*64 + col
  const int tid = threadIdx.x;
  const int lane = tid & 63, wv = tid >> 6;
  const int l15 = lane & 15, lk16 = lane >> 4;
  const int rowbase = blockIdx.x * NBM + wv * 64;
  const short* colbase = e2 + (size_t)(blockIdx.y * CHW) * DF;

  // staging granule G = i*256 + tid: col = lane, k8 = i*4 + wv
  //   src = col*DF + k8*8 shorts ; dst = G*16B (linear, = k8*64+col granule)
  const int src_off = lane * DF + wv * 8;

  auto stage = [&](int tt) {
    const short* nb = colbase + (size_t)tt * NBN * DF + src_off;
    short* db = (short*)ldsB[tt & 1] + tid * 8;
#pragma unroll
    for (int i = 0; i < 8; ++i)
      gload16(nb + i * 32, db + i * 2048);
  };

  stage(0);
  CFENCE();
  // A fragments: 4 m-frags x 8 k-steps (between stage0/stage1; vmcnt(8) at
  // t=0 drains stage0+A, leaves stage1's 8 in flight)
  short8 a[4][8];
#pragma unroll
  for (int mi = 0; mi < 4; ++mi)
#pragma unroll
    for (int ks = 0; ks < 8; ++ks)
      a[mi][ks] = *(const short8*)(e1 + (size_t)(rowbase + mi * 16 + l15) * DF + ks * 32 + lk16 * 8);
  CFENCE();
  stage(1);
  CFENCE();

  float mrun[16], srun[16];
#pragma unroll
  for (int i = 0; i < 16; ++i) { mrun[i] = -1e30f; srun[i] = 0.f; }

  for (int t = 0; t < NT; ++t) {
    if (t < NT - 1) asm volatile("s_waitcnt vmcnt(8)" ::: "memory");
    else            asm volatile("s_waitcnt vmcnt(0)" ::: "memory");
    __builtin_amdgcn_s_barrier();      // buf[t&1] fully staged for all waves
    const short* bbase = (const short*)ldsB[t & 1] + (lk16 * 64 + l15) * 8;

    // two nf-halves: acc[4][2] (32 VGPR) per half, softmax between — keeps
    // total regs ~212 (no spill), trades +16 exps/tile
#pragma unroll
    for (int h = 0; h < 2; ++h) {
      f32x4 acc[4][2];
#pragma unroll
      for (int mi = 0; mi < 4; ++mi)
#pragma unroll
        for (int nf = 0; nf < 2; ++nf) acc[mi][nf] = f32x4{0.f, 0.f, 0.f, 0.f};

      __builtin_amdgcn_s_setprio(1);
#pragma unroll
      for (int ks = 0; ks < 8; ++ks) {
        short8 b0 = *(const short8*)(bbase + ks * 2048 + (h * 2) * 128);
        short8 b1 = *(const short8*)(bbase + ks * 2048 + (h * 2 + 1) * 128);
#pragma unroll
        for (int mi = 0; mi < 4; ++mi) {
          acc[mi][0] = __builtin_amdgcn_mfma_f32_16x16x32_bf16(a[mi][ks], b0, acc[mi][0], 0, 0, 0);
          acc[mi][1] = __builtin_amdgcn_mfma_f32_16x16x32_bf16(a[mi][ks], b1, acc[mi][1], 0, 0, 0);
        }
      }
      __builtin_amdgcn_s_setprio(0);

      // branchless online softmax for this half (always-rescale, raw v_exp)
#pragma unroll
      for (int mi = 0; mi < 4; ++mi)
#pragma unroll
        for (int r = 0; r < 4; ++r) {
          int s16 = mi * 4 + r;
          float v0 = acc[mi][0][r], v1 = acc[mi][1][r];
          float mo = mrun[s16];
          float mn = fmaxf(mo, fmaxf(v0, v1));
          mrun[s16] = mn;
          srun[s16] = srun[s16] * __expf(mo - mn) + __expf(v0 - mn) + __expf(v1 - mn);
        }
    }
    __builtin_amdgcn_s_barrier();      // all waves done reading buf[t&1]
    CFENCE();
    if (t + 2 < NT) stage(t + 2);      // refill just-consumed buffer; stays in flight
  }

  // merge (m,s) across the 16 lanes holding each row, write per-chunk partials
#pragma unroll
  for (int mi = 0; mi < 4; ++mi)
#pragma unroll
    for (int r = 0; r < 4; ++r) {
      int s16 = mi * 4 + r;
      float m = mrun[s16], s = srun[s16];
#pragma unroll
      for (int msk = 1; msk < 16; msk <<= 1) {
        float mo = __shfl_xor(m, msk);
        float so = __shfl_xor(s, msk);
        float mn = fmaxf(m, mo);
        s = s * __expf(m - mn) + so * __expf(mo - mn);
        m = mn;
      }
      if (l15 == 0) {
        int row = rowbase + mi * 16 + lk16 * 4 + r;
        mpart[blockIdx.y * NTOT + row] = m;
        spart[blockIdx.y * NTOT + row] = s;
      }
    }
}

// ---------- kernel 5a: per-row lse - pos (nat-domain partials) ----------
__global__ __launch_bounds__(256) void finalize1_kernel(const float* __restrict__ pos,
                                                        const float* __restrict__ mpart,
                                                        const float* __restrict__ spart,
                                                        float* __restrict__ partial) {
  __shared__ float red[4];
  int row = blockIdx.x * 256 + threadIdx.x;
  float m = -1e30f;
#pragma unroll
  for (int c = 0; c < NCHUNK; ++c) m = fmaxf(m, mpart[c * NTOT + row]);
  float s = 0.f;
#pragma unroll
  for (int c = 0; c < NCHUNK; ++c) s += spart[c * NTOT + row] * __expf(mpart[c * NTOT + row] - m);
  float v = m + LN2 * __builtin_amdgcn_logf(s) - pos[row];
#pragma unroll
  for (int msk = 1; msk < 64; msk <<= 1) v += __shfl_xor(v, msk);
  if ((threadIdx.x & 63) == 0) red[threadIdx.x >> 6] = v;
  __syncthreads();
  if (threadIdx.x == 0) partial[blockIdx.x] = red[0] + red[1] + red[2] + red[3];
}

// ---------- kernel 5b: final scalar ----------
__global__ __launch_bounds__(64) void finalize2_kernel(const float* __restrict__ partial,
                                                       float* __restrict__ out) {
  int lane = threadIdx.x;
  float v = lane < 32 ? partial[lane] : 0.f;
#pragma unroll
  for (int msk = 1; msk < 64; msk <<= 1) v += __shfl_xor(v, msk);
  if (lane == 0) out[0] = v / (float)NTOT - logf((float)NTOT);
}

extern "C" void kernel_launch(void* const* d_in, const int* in_sizes, int n_in,
                              void* d_out, int out_size, void* d_ws, size_t ws_size,
                              hipStream_t stream) {
  const float* f1 = (const float*)d_in[0];
  const float* f2 = (const float*)d_in[1];
  const float* W = (const float*)d_in[2];
  const float* bias = (const float*)d_in[3];
  const int* prs = (const int*)d_in[4];
  const int* prt = (const int*)d_in[5];
  float* out = (float*)d_out;

  char* ws = (char*)d_ws;
  short* Wt = (short*)(ws);                                  // 256 KB @ 0
  short* emb1 = (short*)(ws + 262144);                       // 4 MB
  short* emb2 = (short*)(ws + 262144 + 4194304);             // 4 MB
  float* pos = (float*)(ws + 8650752);                       // 32 KB
  float* mpart = (float*)(ws + 8683520);                     // 512 KB
  float* spart = (float*)(ws + 9207808);                     // 512 KB
  float* partial = (float*)(ws + 9732096);                   // 128 B

  prep_w_kernel<<<32, 256, 0, stream>>>(W, Wt);
  proj_kernel<<<dim3(NTOT / PBM, 2), 256, 0, stream>>>(f1, f2, Wt, bias, emb1, emb2);
  positive_kernel<<<NTOT / POSR, 256, 0, stream>>>(emb1, emb2, prs, prt, pos);
  negative_kernel<<<dim3(NTOT / NBM, NCHUNK), 256, 0, stream>>>(emb1, emb2, mpart, spart);
  finalize1_kernel<<<32, 256, 0, stream>>>(pos, mpart, spart, partial);
  finalize2_kernel<<<1, 64, 0, stream>>>(partial, out);
}

// Round 12
// 96.646 us; speedup vs baseline: 1.1038x; 1.1038x over previous
//
#include <hip/hip_runtime.h>
#include <hip/hip_bf16.h>
#include <math.h>

#define DIN 512
#define DF 256
#define LSEQ 1024
#define NTOT 8192

typedef __attribute__((ext_vector_type(8))) short short8;
typedef __attribute__((ext_vector_type(4))) short short4v;
typedef __attribute__((ext_vector_type(4))) float f32x4;

__device__ __forceinline__ short f2bf(float x) {
  union { float f; unsigned u; } un; un.f = x;
  unsigned r = un.u + 0x7fffu + ((un.u >> 16) & 1u);  // RNE (inputs finite)
  return (short)(r >> 16);
}
__device__ __forceinline__ float bf2f(short s) {
  union { unsigned u; float f; } un; un.u = ((unsigned)(unsigned short)s) << 16;
  return un.f;
}

typedef __attribute__((address_space(1))) const unsigned char AS1c;
typedef __attribute__((address_space(3))) unsigned char AS3;
__device__ __forceinline__ void gload16(const void* g, void* l) {
  __builtin_amdgcn_global_load_lds((AS1c*)g, (AS3*)l, 16, 0, 0);
}
#define CFENCE() asm volatile("" ::: "memory")
#define LN2 0.69314718056f

// ---------- kernel 1: W [DIN][DF] f32 -> Wt [DF][DIN] bf16 (LDS transpose) ----
__global__ __launch_bounds__(256) void prep_w_kernel(const float* __restrict__ W,
                                                     short* __restrict__ Wt) {
  __shared__ short t[64 * 70];
  const int tid = threadIdx.x;
  const int k0 = (blockIdx.x & 7) * 64;    // 8 k-tiles
  const int c0 = (blockIdx.x >> 3) * 64;   // 4 c-tiles
  const int cl = tid & 63, kq = tid >> 6;  // read: c fast (coalesced)
#pragma unroll
  for (int r = 0; r < 16; ++r) {
    int kl = kq * 16 + r;
    t[cl * 70 + kl] = f2bf(W[(size_t)(k0 + kl) * DF + c0 + cl]);
  }
  __syncthreads();
  const int kl2 = tid & 63, cq = tid >> 6; // write: k fast (coalesced)
#pragma unroll
  for (int r = 0; r < 16; ++r) {
    int cl2 = cq * 16 + r;
    Wt[(size_t)(c0 + cl2) * DIN + k0 + kl2] = t[cl2 * 70 + kl2];
  }
}

// ---------- kernel 2: projection emb = relu(feat @ W + b), bf16 out ----------
#define PBM 64
#define PBK 64

__global__ __launch_bounds__(256) void proj_kernel(const float* __restrict__ f1,
                                                   const float* __restrict__ f2,
                                                   const short* __restrict__ Wt,
                                                   const float* __restrict__ bias,
                                                   short* __restrict__ emb1,
                                                   short* __restrict__ emb2) {
  const float* feat = blockIdx.y ? f2 : f1;
  short* emb = blockIdx.y ? emb2 : emb1;
  __shared__ short ldsA[8 * 64 * 8];    // 8KB:  granule g = kb*64 + row
  __shared__ short ldsB[8 * 256 * 8];   // 32KB: granule g = kb*256 + col
  const int tid = threadIdx.x;
  const int lane = tid & 63, wv = tid >> 6;
  const int wrow = (wv & 1) * 32, wcol = (wv >> 1) * 128;
  const int l15 = lane & 15, lk16 = lane >> 4;
  const int rowbase = blockIdx.x * PBM;

  f32x4 acc[2][8];
#pragma unroll
  for (int mi = 0; mi < 2; ++mi)
#pragma unroll
    for (int nf = 0; nf < 8; ++nf) acc[mi][nf] = f32x4{0.f, 0.f, 0.f, 0.f};

  for (int K0 = 0; K0 < DIN; K0 += PBK) {
    __syncthreads();
#pragma unroll
    for (int i = 0; i < 8; ++i)
      gload16(Wt + (size_t)tid * DIN + K0 + i * 8, ldsB + (i * 256 + tid) * 8);
#pragma unroll
    for (int i = 0; i < 2; ++i) {
      int g = i * 256 + tid;
      int kb = g >> 6, r = g & 63;
      const float* src = feat + (size_t)(rowbase + r) * DIN + K0 + kb * 8;
      f32x4 v0 = *(const f32x4*)(src);
      f32x4 v1 = *(const f32x4*)(src + 4);
      short8 h;
      h[0] = f2bf(v0[0]); h[1] = f2bf(v0[1]); h[2] = f2bf(v0[2]); h[3] = f2bf(v0[3]);
      h[4] = f2bf(v1[0]); h[5] = f2bf(v1[1]); h[6] = f2bf(v1[2]); h[7] = f2bf(v1[3]);
      *(short8*)(ldsA + g * 8) = h;
    }
    __syncthreads();
#pragma unroll
    for (int kk = 0; kk < 2; ++kk) {
      const int kb = kk * 4 + lk16;
      short8 af[2], bf[8];
#pragma unroll
      for (int mi = 0; mi < 2; ++mi)
        af[mi] = *(const short8*)(ldsA + (kb * 64 + wrow + mi * 16 + l15) * 8);
#pragma unroll
      for (int nf = 0; nf < 8; ++nf)
        bf[nf] = *(const short8*)(ldsB + (kb * 256 + wcol + nf * 16 + l15) * 8);
#pragma unroll
      for (int mi = 0; mi < 2; ++mi)
#pragma unroll
        for (int nf = 0; nf < 8; ++nf)
          acc[mi][nf] = __builtin_amdgcn_mfma_f32_16x16x32_bf16(af[mi], bf[nf], acc[mi][nf], 0, 0, 0);
    }
  }
  const int r4 = (lane >> 4) * 4;
#pragma unroll
  for (int mi = 0; mi < 2; ++mi) {
    int row0 = rowbase + wrow + mi * 16 + r4;
#pragma unroll
    for (int nf = 0; nf < 8; ++nf) {
      int col = wcol + nf * 16 + l15;
      float bb = bias[col];
#pragma unroll
      for (int r = 0; r < 4; ++r) {
        float v = acc[mi][nf][r] + bb;
        v = v > 0.f ? v : 0.f;
        emb[(size_t)(row0 + r) * DF + col] = f2bf(v);
      }
    }
  }
}

// ---------- kernel 3: positive = dot(e1,e2) + banded diag means (LDS halo) ----
#define POSR 32
#define PSTR 258   // row stride in shorts (4B pad)

__global__ __launch_bounds__(256) void positive_kernel(const short* __restrict__ emb1,
                                                       const short* __restrict__ emb2,
                                                       const int* __restrict__ prs,
                                                       const int* __restrict__ prt,
                                                       float* __restrict__ pos) {
  __shared__ short s1[40 * PSTR];
  __shared__ short s2[40 * PSTR];
  const int tid = threadIdx.x;
  const int b = blockIdx.x >> 5;          // 32 blocks per batch
  const int j0 = (blockIdx.x & 31) * POSR;
  const int rs = prs[0], rt = prt[0];

  {
    const int rr = tid >> 6, c4 = (tid & 63) * 4;
#pragma unroll
    for (int it = 0; it < 10; ++it) {
      int r = it * 4 + rr;
      int g = j0 - 4 + r;
      short4v v1 = short4v{0, 0, 0, 0}, v2 = short4v{0, 0, 0, 0};
      if (g >= 0 && g < LSEQ) {
        size_t off = (size_t)(b * LSEQ + g) * DF + c4;
        v1 = *(const short4v*)(emb1 + off);
        v2 = *(const short4v*)(emb2 + off);
      }
      *(short4v*)(s1 + r * PSTR + c4) = v1;
      *(short4v*)(s2 + r * PSTR + c4) = v2;
    }
  }
  __syncthreads();

  const int lane = tid & 63, wv = tid >> 6;
  for (int q = 0; q < 8; ++q) {
    const int j = j0 + wv * 8 + q;
    const int rl = wv * 8 + q + 4;
    float a1[4], a2[4];
    {
      short4v v1 = *(const short4v*)(s1 + rl * PSTR + lane * 4);
      short4v v2 = *(const short4v*)(s2 + rl * PSTR + lane * 4);
#pragma unroll
      for (int i = 0; i < 4; ++i) { a1[i] = bf2f(v1[i]); a2[i] = bf2f(v2[i]); }
    }
    float dot12 = 0.f, p11 = 0.f, p22 = 0.f, p12 = 0.f;
#pragma unroll
    for (int i = 0; i < 4; ++i) dot12 += a1[i] * a2[i];
    int rmax = rs > rt ? rs : rt;
    for (int d = -rmax; d <= rmax; ++d) {
      int k = j + d;
      if (k < 0 || k >= LSEQ) continue;
      int kl = rl + d;
      short4v w1 = *(const short4v*)(s1 + kl * PSTR + lane * 4);
      short4v w2 = *(const short4v*)(s2 + kl * PSTR + lane * 4);
      float d11 = 0.f, d22 = 0.f, d12 = 0.f;
#pragma unroll
      for (int i = 0; i < 4; ++i) {
        float e1k = bf2f(w1[i]), e2k = bf2f(w2[i]);
        d11 += a1[i] * e1k;
        d22 += a2[i] * e2k;
        d12 += a1[i] * e2k;
      }
      if (d >= -rs && d <= rs) { p11 += d11; p22 += d22; }
      if (d >= -rt && d <= rt) { p12 += d12; }
    }
#pragma unroll
    for (int m = 1; m < 64; m <<= 1) {
      dot12 += __shfl_xor(dot12, m);
      p11 += __shfl_xor(p11, m);
      p22 += __shfl_xor(p22, m);
      p12 += __shfl_xor(p12, m);
    }
    if (lane == 0) {
      float res = dot12;
      if (rs > 0) {
        int lo = j - rs < 0 ? 0 : j - rs;
        int hi = j + rs > LSEQ - 1 ? LSEQ - 1 : j + rs;
        res += (p11 + p22) / (float)(hi - lo + 1);
      }
      if (rt > 0) {
        int lo = j - rt < 0 ? 0 : j - rt;
        int hi = j + rt > LSEQ - 1 ? LSEQ - 1 : j + rt;
        res += p12 / (float)(hi - lo + 1);
      }
      pos[b * LSEQ + j] = res;
    }
  }
}

// ---------- kernel 4: flash-style row logsumexp of e1 @ e2^T ----------
// ROUND-0 CHAMPION STRUCTURE, byte-for-byte (46.3us, best of 11 rounds):
// 128 rows/block (4 waves x 32 rows), A (K=256) in regs; NBN=64 (half the
// barriers-per-MFMA of the NBN=32 variants); SINGLE 32KB LDS buffer with
// REGISTER double-buffering (st[8] prefetch, compiler-placed vmcnt);
// full-drain __syncthreads x2 per tile; slot = kblk ^ (c&7) swizzle.
// ONE change: NCHUNK 8 -> 16 => grid 1024 blocks = 4 resident blocks/CU
// (was 2 available at 512) — doubles independent convoys per CU.
#define NBM 128
#define NBN 64
#define NCHUNK 16
#define CHW (NTOT / NCHUNK)   // 512
#define NT (CHW / NBN)        // 8

__global__ __launch_bounds__(256) void negative_kernel(const short* __restrict__ e1,
                                                       const short* __restrict__ e2,
                                                       float* __restrict__ mpart,
                                                       float* __restrict__ spart) {
  __shared__ short ldsB[NBN * DF];   // 32KB
  const int tid = threadIdx.x;
  const int lane = tid & 63, wv = tid >> 6;
  const int l15 = lane & 15, lk16 = lane >> 4;
  const int rb = blockIdx.x, chunk = blockIdx.y;
  const int rowbase = rb * NBM + wv * 32;
  const int colbase0 = chunk * CHW;

  // A fragments for this wave's 32 rows, full K=256: 2 m-frags x 8 k-steps
  short8 a[2][8];
#pragma unroll
  for (int mi = 0; mi < 2; ++mi)
#pragma unroll
    for (int ks = 0; ks < 8; ++ks)
      a[mi][ks] = *(const short8*)(e1 + (size_t)(rowbase + mi * 16 + l15) * DF + ks * 32 + lk16 * 8);

  float mrun[8], srun[8];
#pragma unroll
  for (int i = 0; i < 8; ++i) { mrun[i] = -1e30f; srun[i] = 0.f; }

  short8 st[8];
  {
    const short* src = e2 + (size_t)colbase0 * DF;
#pragma unroll
    for (int it = 0; it < 8; ++it) {
      int S = it * 256 + tid;
      int c = S >> 5, kblk = S & 31;
      st[it] = *(const short8*)(src + (size_t)c * DF + kblk * 8);
    }
  }
  for (int t = 0; t < NT; ++t) {
    __syncthreads();
#pragma unroll
    for (int it = 0; it < 8; ++it) {
      int S = it * 256 + tid;
      int c = S >> 5, kblk = S & 31;
      int slot = kblk ^ (c & 7);
      *(short8*)(ldsB + (c * 32 + slot) * 8) = st[it];
    }
    __syncthreads();
    if (t + 1 < NT) {   // prefetch next tile; vmcnt drains at next iter's ds_write
      const short* src = e2 + (size_t)(colbase0 + (t + 1) * NBN) * DF;
#pragma unroll
      for (int it = 0; it < 8; ++it) {
        int S = it * 256 + tid;
        int c = S >> 5, kblk = S & 31;
        st[it] = *(const short8*)(src + (size_t)c * DF + kblk * 8);
      }
    }
    f32x4 acc[2][4];
#pragma unroll
    for (int mi = 0; mi < 2; ++mi)
#pragma unroll
      for (int nf = 0; nf < 4; ++nf) acc[mi][nf] = f32x4{0.f, 0.f, 0.f, 0.f};
#pragma unroll
    for (int ks = 0; ks < 8; ++ks) {
      short8 bfr[4];
#pragma unroll
      for (int nf = 0; nf < 4; ++nf) {
        int c = nf * 16 + l15;
        int kblk = ks * 4 + lk16;
        int slot = kblk ^ (c & 7);
        bfr[nf] = *(const short8*)(ldsB + (c * 32 + slot) * 8);
      }
#pragma unroll
      for (int mi = 0; mi < 2; ++mi)
#pragma unroll
        for (int nf = 0; nf < 4; ++nf)
          acc[mi][nf] = __builtin_amdgcn_mfma_f32_16x16x32_bf16(a[mi][ks], bfr[nf], acc[mi][nf], 0, 0, 0);
    }
    // per-lane online max/sum over this lane's own 4 columns per row-slot
#pragma unroll
    for (int mi = 0; mi < 2; ++mi)
#pragma unroll
      for (int r = 0; r < 4; ++r) {
        int s8 = mi * 4 + r;
        float v0 = acc[mi][0][r], v1 = acc[mi][1][r], v2 = acc[mi][2][r], v3 = acc[mi][3][r];
        float mx = fmaxf(fmaxf(v0, v1), fmaxf(v2, v3));
        float mn = fmaxf(mrun[s8], mx);
        float sc = __expf(mrun[s8] - mn);
        float sm = __expf(v0 - mn) + __expf(v1 - mn) + __expf(v2 - mn) + __expf(v3 - mn);
        srun[s8] = srun[s8] * sc + sm;
        mrun[s8] = mn;
      }
  }
  // merge (m,s) across the 16 lanes (same row) of each lane-group, then write
#pragma unroll
  for (int mi = 0; mi < 2; ++mi)
#pragma unroll
    for (int r = 0; r < 4; ++r) {
      int s8 = mi * 4 + r;
      float m = mrun[s8], s = srun[s8];
#pragma unroll
      for (int msk = 1; msk < 16; msk <<= 1) {
        float mo = __shfl_xor(m, msk);
        float so = __shfl_xor(s, msk);
        float mn = fmaxf(m, mo);
        s = s * __expf(m - mn) + so * __expf(mo - mn);
        m = mn;
      }
      if (l15 == 0) {
        int row = rowbase + mi * 16 + lk16 * 4 + r;
        mpart[chunk * NTOT + row] = m;
        spart[chunk * NTOT + row] = s;
      }
    }
}

// ---------- kernel 5a: per-row lse - pos (nat-domain partials) ----------
__global__ __launch_bounds__(256) void finalize1_kernel(const float* __restrict__ pos,
                                                        const float* __restrict__ mpart,
                                                        const float* __restrict__ spart,
                                                        float* __restrict__ partial) {
  __shared__ float red[4];
  int row = blockIdx.x * 256 + threadIdx.x;
  float m = -1e30f;
#pragma unroll
  for (int c = 0; c < NCHUNK; ++c) m = fmaxf(m, mpart[c * NTOT + row]);
  float s = 0.f;
#pragma unroll
  for (int c = 0; c < NCHUNK; ++c) s += spart[c * NTOT + row] * __expf(mpart[c * NTOT + row] - m);
  float v = m + LN2 * __builtin_amdgcn_logf(s) - pos[row];
#pragma unroll
  for (int msk = 1; msk < 64; msk <<= 1) v += __shfl_xor(v, msk);
  if ((threadIdx.x & 63) == 0) red[threadIdx.x >> 6] = v;
  __syncthreads();
  if (threadIdx.x == 0) partial[blockIdx.x] = red[0] + red[1] + red[2] + red[3];
}

// ---------- kernel 5b: final scalar ----------
__global__ __launch_bounds__(64) void finalize2_kernel(const float* __restrict__ partial,
                                                       float* __restrict__ out) {
  int lane = threadIdx.x;
  float v = lane < 32 ? partial[lane] : 0.f;
#pragma unroll
  for (int msk = 1; msk < 64; msk <<= 1) v += __shfl_xor(v, msk);
  if (lane == 0) out[0] = v / (float)NTOT - logf((float)NTOT);
}

extern "C" void kernel_launch(void* const* d_in, const int* in_sizes, int n_in,
                              void* d_out, int out_size, void* d_ws, size_t ws_size,
                              hipStream_t stream) {
  const float* f1 = (const float*)d_in[0];
  const float* f2 = (const float*)d_in[1];
  const float* W = (const float*)d_in[2];
  const float* bias = (const float*)d_in[3];
  const int* prs = (const int*)d_in[4];
  const int* prt = (const int*)d_in[5];
  float* out = (float*)d_out;

  char* ws = (char*)d_ws;
  short* Wt = (short*)(ws);                                  // 256 KB @ 0
  short* emb1 = (short*)(ws + 262144);                       // 4 MB
  short* emb2 = (short*)(ws + 262144 + 4194304);             // 4 MB
  float* pos = (float*)(ws + 8650752);                       // 32 KB
  float* mpart = (float*)(ws + 8683520);                     // 512 KB
  float* spart = (float*)(ws + 9207808);                     // 512 KB
  float* partial = (float*)(ws + 9732096);                   // 128 B

  prep_w_kernel<<<32, 256, 0, stream>>>(W, Wt);
  proj_kernel<<<dim3(NTOT / PBM, 2), 256, 0, stream>>>(f1, f2, Wt, bias, emb1, emb2);
  positive_kernel<<<NTOT / POSR, 256, 0, stream>>>(emb1, emb2, prs, prt, pos);
  negative_kernel<<<dim3(NTOT / NBM, NCHUNK), 256, 0, stream>>>(emb1, emb2, mpart, spart);
  finalize1_kernel<<<32, 256, 0, stream>>>(pos, mpart, spart, partial);
  finalize2_kernel<<<1, 64, 0, stream>>>(partial, out);
}